// Round 1
// baseline (483.578 us; speedup 1.0000x reference)
//
#include <hip/hip_runtime.h>
#include <hip/hip_bf16.h>

// HMM forward-backward, B=128, T=1024, K=256.
// P = (diag-offd)*I + offd*J  (rank-1 + diagonal, symmetric) -> each
// recursion step is O(K): (v@P)[j] = offd*sum(v) + (diag-offd)*v[j].
// 256 blocks x 64 threads: blocks 0..127 forward(batch), 128..255 backward.
// Each lane owns 4 states (float4 over K=256). Per-step normalization is a
// single 64-lane shuffle reduction (no LDS, no barriers).
// alpha/beta staged as bf16 in d_ws; posterior = normalize(alpha*beta) in a
// second, memory-bound kernel.

constexpr int BB = 128;
constexpr int TT = 1024;
constexpr int KK = 256;
constexpr int CH = 8;   // prefetch chunk depth (rows of x per buffer)

__device__ __forceinline__ float wred(float v) {
  v += __shfl_xor(v, 32, 64);
  v += __shfl_xor(v, 16, 64);
  v += __shfl_xor(v, 8, 64);
  v += __shfl_xor(v, 4, 64);
  v += __shfl_xor(v, 2, 64);
  v += __shfl_xor(v, 1, 64);
  return v;
}

__device__ __forceinline__ float fsig(float x) {
  // sigmoid(x) = 1 / (1 + e^-x); __expf -> v_exp_f32, rcp -> v_rcp_f32.
  return __builtin_amdgcn_rcpf(1.0f + __expf(-x));
}

__device__ __forceinline__ unsigned short f2bf(float f) {
  // round-to-nearest-even f32 -> bf16 (values here are positive finite)
  unsigned int u = __float_as_uint(f);
  return (unsigned short)((u + 0x7FFFu + ((u >> 16) & 1u)) >> 16);
}

__global__ __launch_bounds__(64, 1) void hmm_recur(
    const float* __restrict__ x, const float* __restrict__ P,
    const float* __restrict__ p0,
    __hip_bfloat16* __restrict__ alpha, __hip_bfloat16* __restrict__ beta) {
  const int seq = blockIdx.x;   // 0..255
  const int lane = threadIdx.x; // 0..63
  const float diag = P[0];      // P[0][0]
  const float offd = P[1];      // P[0][1]
  const float cd = diag - offd;
  const float cod = offd;

  if (seq < BB) {
    // ---------------- forward: alpha ----------------
    const int b = seq;
    const float4* xr = reinterpret_cast<const float4*>(x + (size_t)b * TT * KK);
    ushort4* ar = reinterpret_cast<ushort4*>(alpha + (size_t)b * TT * KK);
    const float4 p0v = reinterpret_cast<const float4*>(p0)[lane];

    float a0 = 0.f, a1 = 0.f, a2 = 0.f, a3 = 0.f;
    float4 bufA[CH], bufB[CH];
#pragma unroll
    for (int i = 0; i < CH; ++i) bufA[i] = xr[i * 64 + lane];
#pragma unroll
    for (int i = 0; i < CH; ++i) bufB[i] = xr[(CH + i) * 64 + lane];

    auto runchunkF = [&](const float4* buf, int tbase) {
      float ys[CH][4];
#pragma unroll
      for (int i = 0; i < CH; ++i) {
        ys[i][0] = fsig(buf[i].x);
        ys[i][1] = fsig(buf[i].y);
        ys[i][2] = fsig(buf[i].z);
        ys[i][3] = fsig(buf[i].w);
      }
#pragma unroll
      for (int i = 0; i < CH; ++i) {
        const int t = tbase + i;
        float v0, v1, v2, v3;
        if (t == 0) {
          v0 = p0v.x * ys[i][0];
          v1 = p0v.y * ys[i][1];
          v2 = p0v.z * ys[i][2];
          v3 = p0v.w * ys[i][3];
        } else {
          v0 = (cod + cd * a0) * ys[i][0];
          v1 = (cod + cd * a1) * ys[i][1];
          v2 = (cod + cd * a2) * ys[i][2];
          v3 = (cod + cd * a3) * ys[i][3];
        }
        const float s = wred((v0 + v1) + (v2 + v3));
        const float r = __builtin_amdgcn_rcpf(s);
        a0 = v0 * r; a1 = v1 * r; a2 = v2 * r; a3 = v3 * r;
        ushort4 pk;
        pk.x = f2bf(a0); pk.y = f2bf(a1); pk.z = f2bf(a2); pk.w = f2bf(a3);
        ar[t * 64 + lane] = pk;
      }
    };

    for (int tc = 0; tc < TT; tc += 2 * CH) {
      runchunkF(bufA, tc);
      if (tc + 2 * CH < TT) {
#pragma unroll
        for (int i = 0; i < CH; ++i) bufA[i] = xr[(tc + 2 * CH + i) * 64 + lane];
      }
      runchunkF(bufB, tc + CH);
      if (tc + 3 * CH < TT) {
#pragma unroll
        for (int i = 0; i < CH; ++i) bufB[i] = xr[(tc + 3 * CH + i) * 64 + lane];
      }
    }
  } else {
    // ---------------- backward: beta ----------------
    const int b = seq - BB;
    const float4* xr = reinterpret_cast<const float4*>(x + (size_t)b * TT * KK);
    ushort4* br = reinterpret_cast<ushort4*>(beta + (size_t)b * TT * KK);
    const float sumfac = (float)KK * cod + cd;  // sum(beta') = Sv * sumfac

    float b0 = 1.f, b1 = 1.f, b2 = 1.f, b3 = 1.f;
    float4 bufA[CH], bufB[CH];

    auto loadB = [&](float4* buf, int ubase) {
#pragma unroll
      for (int i = 0; i < CH; ++i) {
        const int u = ubase + i;
        const int row = (u == 0) ? (TT - 1) : (TT - u);  // u=0 row unused
        buf[i] = xr[row * 64 + lane];
      }
    };
    loadB(bufA, 0);
    loadB(bufB, CH);

    auto runchunkB = [&](const float4* buf, int ubase) {
      float ys[CH][4];
#pragma unroll
      for (int i = 0; i < CH; ++i) {
        ys[i][0] = fsig(buf[i].x);
        ys[i][1] = fsig(buf[i].y);
        ys[i][2] = fsig(buf[i].z);
        ys[i][3] = fsig(buf[i].w);
      }
#pragma unroll
      for (int i = 0; i < CH; ++i) {
        const int u = ubase + i;
        if (u == 0) {
          ushort4 pk;
          pk.x = pk.y = pk.z = pk.w = (unsigned short)0x3F80;  // bf16 1.0
          br[(TT - 1) * 64 + lane] = pk;
          b0 = b1 = b2 = b3 = 1.f;
        } else {
          const float v0 = ys[i][0] * b0;
          const float v1 = ys[i][1] * b1;
          const float v2 = ys[i][2] * b2;
          const float v3 = ys[i][3] * b3;
          const float sv = wred((v0 + v1) + (v2 + v3));
          const float sc = __builtin_amdgcn_rcpf(sv * sumfac);
          b0 = (cod * sv + cd * v0) * sc;
          b1 = (cod * sv + cd * v1) * sc;
          b2 = (cod * sv + cd * v2) * sc;
          b3 = (cod * sv + cd * v3) * sc;
          ushort4 pk;
          pk.x = f2bf(b0); pk.y = f2bf(b1); pk.z = f2bf(b2); pk.w = f2bf(b3);
          br[(TT - 1 - u) * 64 + lane] = pk;
        }
      }
    };

    for (int uc = 0; uc < TT; uc += 2 * CH) {
      runchunkB(bufA, uc);
      if (uc + 2 * CH < TT) loadB(bufA, uc + 2 * CH);
      runchunkB(bufB, uc + CH);
      if (uc + 3 * CH < TT) loadB(bufB, uc + 3 * CH);
    }
  }
}

__global__ __launch_bounds__(256) void hmm_post(
    const __hip_bfloat16* __restrict__ alpha,
    const __hip_bfloat16* __restrict__ beta, float* __restrict__ out) {
  const long long gid = (long long)blockIdx.x * 256 + threadIdx.x;
  const long long row = gid >> 6;  // one wave per (b,t) row
  const int lane = (int)(gid & 63);
  const ushort4 av = reinterpret_cast<const ushort4*>(alpha)[row * 64 + lane];
  const ushort4 bv = reinterpret_cast<const ushort4*>(beta)[row * 64 + lane];
  const float g0 = __uint_as_float((unsigned)av.x << 16) * __uint_as_float((unsigned)bv.x << 16);
  const float g1 = __uint_as_float((unsigned)av.y << 16) * __uint_as_float((unsigned)bv.y << 16);
  const float g2 = __uint_as_float((unsigned)av.z << 16) * __uint_as_float((unsigned)bv.z << 16);
  const float g3 = __uint_as_float((unsigned)av.w << 16) * __uint_as_float((unsigned)bv.w << 16);
  const float s = wred((g0 + g1) + (g2 + g3));
  const float r = __builtin_amdgcn_rcpf(s);
  float4 o;
  o.x = g0 * r; o.y = g1 * r; o.z = g2 * r; o.w = g3 * r;
  reinterpret_cast<float4*>(out)[row * 64 + lane] = o;
}

extern "C" void kernel_launch(void* const* d_in, const int* in_sizes, int n_in,
                              void* d_out, int out_size, void* d_ws, size_t ws_size,
                              hipStream_t stream) {
  const float* x = (const float*)d_in[0];
  const float* P = (const float*)d_in[1];
  const float* p0 = (const float*)d_in[2];
  float* out = (float*)d_out;
  __hip_bfloat16* alpha = (__hip_bfloat16*)d_ws;                 // 64 MB
  __hip_bfloat16* beta = alpha + (size_t)BB * TT * KK;           // 64 MB

  hmm_recur<<<2 * BB, 64, 0, stream>>>(x, P, p0, alpha, beta);
  hmm_post<<<(BB * TT) / 4, 256, 0, stream>>>(alpha, beta, out);
}

// Round 2
// 367.261 us; speedup vs baseline: 1.3167x; 1.3167x over previous
//
#include <hip/hip_runtime.h>
#include <hip/hip_bf16.h>
#include <type_traits>

// HMM forward-backward, B=128, T=1024, K=256.
// P = (diag-offd)*I + offd*J  -> (v@P)[j] = offd*sum(v) + (diag-offd)*v[j].
// R2: DPP-based wave reduction (no LDS shuffles), deferred normalization
// (posterior is scale-invariant per row; rescale fp32 state every 16 steps),
// sigmoid hoisted into a parallel pass writing bf16 y, 4-deep ring prefetch.

constexpr int BB = 128;
constexpr int TT = 1024;
constexpr int KK = 256;

// ---------- DPP wave-64 sum reduction -> broadcast scalar ----------
template <int CTRL, int RM>
__device__ __forceinline__ float dpp_add(float v) {
  int t = __builtin_amdgcn_update_dpp(0, __float_as_int(v), CTRL, RM, 0xf, true);
  return v + __int_as_float(t);
}

__device__ __forceinline__ float wred_dpp(float v) {
  v = dpp_add<0x111, 0xf>(v);  // row_shr:1
  v = dpp_add<0x112, 0xf>(v);  // row_shr:2
  v = dpp_add<0x114, 0xf>(v);  // row_shr:4
  v = dpp_add<0x118, 0xf>(v);  // row_shr:8  -> lane 15 of each row = row sum
  v = dpp_add<0x142, 0xa>(v);  // row_bcast:15 -> lane31=r0+r1, lane63=r2+r3
  v = dpp_add<0x143, 0xc>(v);  // row_bcast:31 -> lane63 = total
  return __int_as_float(__builtin_amdgcn_readlane(__float_as_int(v), 63));
}

__device__ __forceinline__ float fsig(float x) {
  return __builtin_amdgcn_rcpf(1.0f + __expf(-x));
}

__device__ __forceinline__ unsigned short f2bf(float f) {  // RNE f32->bf16
  unsigned int u = __float_as_uint(f);
  return (unsigned short)((u + 0x7FFFu + ((u >> 16) & 1u)) >> 16);
}
__device__ __forceinline__ float bf2f(unsigned short u) {
  return __uint_as_float((unsigned)u << 16);
}

// ---------- pass 0: y = sigmoid(x), bf16 ----------
__global__ __launch_bounds__(256) void sig_pass(const float* __restrict__ x,
                                                __hip_bfloat16* __restrict__ y) {
  const size_t i = (size_t)blockIdx.x * 256 + threadIdx.x;
  const float4 v = reinterpret_cast<const float4*>(x)[i];
  ushort4 o;
  o.x = f2bf(fsig(v.x));
  o.y = f2bf(fsig(v.y));
  o.z = f2bf(fsig(v.z));
  o.w = f2bf(fsig(v.w));
  reinterpret_cast<ushort4*>(y)[i] = o;
}

__device__ __forceinline__ float4 to_y(float4 v) {
  return make_float4(fsig(v.x), fsig(v.y), fsig(v.z), fsig(v.w));
}
__device__ __forceinline__ float4 to_y(ushort4 v) {
  return make_float4(bf2f(v.x), bf2f(v.y), bf2f(v.z), bf2f(v.w));
}

// ---------- pass 1: forward/backward recursions ----------
// FUSED=true  : src = x (float32), sigmoid computed inline (ws fallback)
// FUSED=false : src = y (bf16) from sig_pass
template <bool FUSED>
__global__ __launch_bounds__(64, 1) void hmm_recur(
    const void* __restrict__ src, const float* __restrict__ P,
    const float* __restrict__ p0,
    __hip_bfloat16* __restrict__ alpha, __hip_bfloat16* __restrict__ beta) {
  using VecT = typename std::conditional<FUSED, float4, ushort4>::type;
  const int seq = blockIdx.x;   // 0..255
  const int lane = threadIdx.x; // 0..63
  const float diag = P[0];
  const float offd = P[1];
  const float cd = diag - offd;
  const float cod = offd;

  if (seq < BB) {
    // ---------------- forward: alpha (unnormalized) ----------------
    const int b = seq;
    const VecT* srcv = reinterpret_cast<const VecT*>(src) + (size_t)b * TT * 64;
    ushort4* ar = reinterpret_cast<ushort4*>(alpha + (size_t)b * TT * KK);
    const float4 p0v = reinterpret_cast<const float4*>(p0)[lane];

    float v0 = 0.f, v1 = 0.f, v2 = 0.f, v3 = 0.f, S = 1.f;
    VecT bf0[8], bf1[8], bf2[8], bf3[8];

    auto loadF = [&](VecT* buf, int rbase) {
      if (rbase < TT) {
#pragma unroll
        for (int i = 0; i < 8; ++i) buf[i] = srcv[(size_t)(rbase + i) * 64 + lane];
      }
    };
    auto runF = [&](const VecT* buf, int tbase) {
#pragma unroll
      for (int i = 0; i < 8; ++i) {
        const int t = tbase + i;
        const float4 y = to_y(buf[i]);
        float w0, w1, w2, w3;
        if (t == 0) {
          w0 = p0v.x * y.x; w1 = p0v.y * y.y; w2 = p0v.z * y.z; w3 = p0v.w * y.w;
        } else {
          const float codS = cod * S;
          w0 = (codS + cd * v0) * y.x;
          w1 = (codS + cd * v1) * y.y;
          w2 = (codS + cd * v2) * y.z;
          w3 = (codS + cd * v3) * y.w;
        }
        S = wred_dpp((w0 + w1) + (w2 + w3));
        ushort4 pk;
        pk.x = f2bf(w0); pk.y = f2bf(w1); pk.z = f2bf(w2); pk.w = f2bf(w3);
        ar[t * 64 + lane] = pk;
        if ((t & 15) == 15) {  // periodic rescale, off critical path 15/16 steps
          const float r = __builtin_amdgcn_rcpf(S);
          w0 *= r; w1 *= r; w2 *= r; w3 *= r; S = 1.f;
        }
        v0 = w0; v1 = w1; v2 = w2; v3 = w3;
      }
    };

    loadF(bf0, 0); loadF(bf1, 8); loadF(bf2, 16);
    for (int tc = 0; tc < TT; tc += 32) {
      loadF(bf3, tc + 24); runF(bf0, tc);
      loadF(bf0, tc + 32); runF(bf1, tc + 8);
      loadF(bf1, tc + 40); runF(bf2, tc + 16);
      loadF(bf2, tc + 48); runF(bf3, tc + 24);
    }
  } else {
    // ---------------- backward: beta (unnormalized) ----------------
    const int b = seq - BB;
    const VecT* srcv = reinterpret_cast<const VecT*>(src) + (size_t)b * TT * 64;
    ushort4* br = reinterpret_cast<ushort4*>(beta + (size_t)b * TT * KK);

    float b0 = 1.f, b1 = 1.f, b2 = 1.f, b3 = 1.f;
    VecT bf0[8], bf1[8], bf2[8], bf3[8];

    auto loadB = [&](VecT* buf, int ubase) {
      if (ubase < TT) {
#pragma unroll
        for (int i = 0; i < 8; ++i) {
          const int u = ubase + i;
          const int row = (u == 0) ? (TT - 1) : (TT - u);  // u=0 row unused
          buf[i] = srcv[(size_t)row * 64 + lane];
        }
      }
    };
    auto runB = [&](const VecT* buf, int ubase) {
#pragma unroll
      for (int i = 0; i < 8; ++i) {
        const int u = ubase + i;
        if (u == 0) {
          ushort4 pk;
          pk.x = pk.y = pk.z = pk.w = (unsigned short)0x3F80;  // bf16 1.0
          br[(TT - 1) * 64 + lane] = pk;
          b0 = b1 = b2 = b3 = 1.f;
        } else {
          const float4 y = to_y(buf[i]);
          const float w0 = y.x * b0, w1 = y.y * b1, w2 = y.z * b2, w3 = y.w * b3;
          const float Sv = wred_dpp((w0 + w1) + (w2 + w3));
          const float codS = cod * Sv;
          b0 = codS + cd * w0;
          b1 = codS + cd * w1;
          b2 = codS + cd * w2;
          b3 = codS + cd * w3;
          ushort4 pk;
          pk.x = f2bf(b0); pk.y = f2bf(b1); pk.z = f2bf(b2); pk.w = f2bf(b3);
          br[(TT - 1 - u) * 64 + lane] = pk;
          if ((u & 15) == 15) {
            const float r = __builtin_amdgcn_rcpf(Sv);
            b0 *= r; b1 *= r; b2 *= r; b3 *= r;
          }
        }
      }
    };

    loadB(bf0, 0); loadB(bf1, 8); loadB(bf2, 16);
    for (int uc = 0; uc < TT; uc += 32) {
      loadB(bf3, uc + 24); runB(bf0, uc);
      loadB(bf0, uc + 32); runB(bf1, uc + 8);
      loadB(bf1, uc + 40); runB(bf2, uc + 16);
      loadB(bf2, uc + 48); runB(bf3, uc + 24);
    }
  }
}

// ---------- pass 2: posterior = normalize(alpha*beta) ----------
__global__ __launch_bounds__(256) void hmm_post(
    const __hip_bfloat16* __restrict__ alpha,
    const __hip_bfloat16* __restrict__ beta, float* __restrict__ out) {
  const size_t gid = (size_t)blockIdx.x * 256 + threadIdx.x;
  const size_t row = gid >> 6;  // one wave per (b,t) row
  const int lane = (int)(gid & 63);
  const ushort4 av = reinterpret_cast<const ushort4*>(alpha)[row * 64 + lane];
  const ushort4 bv = reinterpret_cast<const ushort4*>(beta)[row * 64 + lane];
  const float g0 = bf2f(av.x) * bf2f(bv.x);
  const float g1 = bf2f(av.y) * bf2f(bv.y);
  const float g2 = bf2f(av.z) * bf2f(bv.z);
  const float g3 = bf2f(av.w) * bf2f(bv.w);
  const float s = wred_dpp((g0 + g1) + (g2 + g3));
  const float r = __builtin_amdgcn_rcpf(s);
  float4 o;
  o.x = g0 * r; o.y = g1 * r; o.z = g2 * r; o.w = g3 * r;
  reinterpret_cast<float4*>(out)[row * 64 + lane] = o;
}

extern "C" void kernel_launch(void* const* d_in, const int* in_sizes, int n_in,
                              void* d_out, int out_size, void* d_ws, size_t ws_size,
                              hipStream_t stream) {
  const float* x = (const float*)d_in[0];
  const float* P = (const float*)d_in[1];
  const float* p0 = (const float*)d_in[2];
  float* out = (float*)d_out;
  const size_t elems = (size_t)BB * TT * KK;

  __hip_bfloat16* alpha = (__hip_bfloat16*)d_ws;       // 64 MB
  __hip_bfloat16* beta = alpha + elems;                // 64 MB

  if (ws_size >= elems * 2 * 3) {
    __hip_bfloat16* y = beta + elems;                  // 64 MB
    sig_pass<<<(int)(elems / 4 / 256), 256, 0, stream>>>(x, y);
    hmm_recur<false><<<2 * BB, 64, 0, stream>>>((const void*)y, P, p0, alpha, beta);
  } else {
    hmm_recur<true><<<2 * BB, 64, 0, stream>>>((const void*)x, P, p0, alpha, beta);
  }
  hmm_post<<<(BB * TT) / 4, 256, 0, stream>>>(alpha, beta, out);
}